// Round 3
// baseline (2605.111 us; speedup 1.0000x reference)
//
#include <hip/hip_runtime.h>
#include <hip/hip_cooperative_groups.h>

namespace cg = cooperative_groups;

#define N_LOC 500000
#define C 128
#define A 24
#define AC 152          // A + C
#define H 256
#define X 128
#define G3 768          // 3*H
#define GRID_BIG 1024
#define MSCALE 64.0f    // contents stored as fp8(e4m3) of 64*value (dodges denorm cliff)
#define MINV 0.015625f  // 1/64

typedef unsigned short ushort_t;
typedef unsigned char uchar_t;
typedef float floatx2 __attribute__((ext_vector_type(2)));

__device__ __forceinline__ float sigmoidf_(float x) { return 1.0f / (1.0f + __expf(-x)); }

__device__ __forceinline__ ushort_t f2bf(float f) {
    unsigned u = __float_as_uint(f);
    u += 0x7FFFu + ((u >> 16) & 1u);
    return (ushort_t)(u >> 16);
}
__device__ __forceinline__ float bf2f(ushort_t s) {
    return __uint_as_float(((unsigned)s) << 16);
}

#if defined(__has_builtin)
#if __has_builtin(__builtin_amdgcn_cvt_pk_fp8_f32) && __has_builtin(__builtin_amdgcn_cvt_pk_f32_fp8)
#define HAVE_HW_FP8 1
#endif
#endif

__device__ __forceinline__ unsigned f2fp8_sw(float f) {
    unsigned sgn = (__float_as_uint(f) >> 24) & 0x80u;
    float af = fminf(fabsf(f), 448.0f);
    unsigned q;
    if (af < 0.015625f) {
        q = (unsigned)__float2int_rn(af * 512.0f);
    } else {
        unsigned a = __float_as_uint(af);
        a += 0x7FFFFu + ((a >> 20) & 1u);
        unsigned e = (a >> 23) - 120u;
        q = (e << 3) | ((a >> 20) & 7u);
        if (q > 126u) q = 126u;
    }
    return q | sgn;
}
__device__ __forceinline__ float fp8d_sw(unsigned b) {
    unsigned sgn = (b & 0x80u) << 24;
    unsigned e = (b >> 3) & 15u;
    unsigned m = b & 7u;
    float fn = __uint_as_float(sgn | ((e + 120u) << 23) | (m << 20));
    float fd = __uint_as_float(sgn | __float_as_uint((float)m * 0.001953125f));
    return e ? fn : fd;
}
__device__ __forceinline__ unsigned pack_fp8x4(float4 m) {
#ifdef HAVE_HW_FP8
    int w = 0;
    w = __builtin_amdgcn_cvt_pk_fp8_f32(m.x, m.y, w, false);
    w = __builtin_amdgcn_cvt_pk_fp8_f32(m.z, m.w, w, true);
    return (unsigned)w;
#else
    return f2fp8_sw(m.x) | (f2fp8_sw(m.y) << 8) | (f2fp8_sw(m.z) << 16) | (f2fp8_sw(m.w) << 24);
#endif
}
__device__ __forceinline__ float4 unpack_fp8x4(unsigned w) {
#ifdef HAVE_HW_FP8
    floatx2 lo = __builtin_amdgcn_cvt_pk_f32_fp8((int)w, false);
    floatx2 hi = __builtin_amdgcn_cvt_pk_f32_fp8((int)w, true);
    return make_float4(lo[0], lo[1], hi[0], hi[1]);
#else
    return make_float4(fp8d_sw(w & 255u), fp8d_sw((w >> 8) & 255u),
                       fp8d_sw((w >> 16) & 255u), fp8d_sw(w >> 24));
#endif
}

// ---------------------------------------------------------------------------
// All device pointers for the persistent kernel.
// ---------------------------------------------------------------------------
struct Params {
    const float *x, *h0, *mem0, *addr;
    const float *W_q, *b_q, *u_sh, *b_sh, *W_er, *b_er, *W_ch, *W_cx, *b_cd;
    const float *W_ih, *W_hh, *b_ih, *b_hh;
    float *hout;
    float *e;            // [3][N_LOC]
    uchar_t *memq;       // [N_LOC][C] fp8 (x64 domain)
    ushort_t *addrbf;    // [N_LOC][A] bf16
    float *craw;         // [132] atomic: content cols (x64) + denom at [C]
    float *qacc;         // [160]: q[0..151], sharpen raw at [152]
    float *ehist;        // [5][128] raw erase pre-sigmoid (slot s from h_s)
    float *chist;        // [5][128] raw cand pre-relu
    float *gix;          // [768] x@W_ih + b_ih
    float *candx;        // [128] x@W_cx
    float *ssum4;        // [8] softmax denom per step
    float *gacc;         // [1536]: gi[768] | gh[768]
    float *hbuf;         // [256] running h
    unsigned *counter;   // [1]
};

// ---------------------------------------------------------------------------
// BIG streaming phase (device function; atomics into craw).
// ---------------------------------------------------------------------------
template <int NPREV, bool WRITE_E, bool CONVERT>
__device__ void big_body(const Params& P, float* __restrict__ enew,
                         float (*sc)[C], float* ssum)
{
    const int lane = threadIdx.x & 31;
    const int rg   = threadIdx.x >> 5;
    const float* qacc = P.qacc;

    float4 qc = *(const float4*)(qacc + A + 4 * lane);
    qc.x *= MINV; qc.y *= MINV; qc.z *= MINV; qc.w *= MINV;
    float4 qa = make_float4(0.f, 0.f, 0.f, 0.f);
    if (lane < 6) qa = *(const float4*)(qacc + 4 * lane);
    float beta;
    { float t = qacc[AC]; beta = (t > 20.f ? t : log1pf(__expf(t))) + 1.0f; }

    constexpr int NP = (NPREV > 0) ? NPREV : 1;
    float4 er[NP], cd[NP];
    float inv_s[NP];
#pragma unroll
    for (int s = 0; s < NPREV; ++s) {
        float4 et = *(const float4*)(P.ehist + (s + 1) * C + 4 * lane);
        er[s].x = sigmoidf_(et.x); er[s].y = sigmoidf_(et.y);
        er[s].z = sigmoidf_(et.z); er[s].w = sigmoidf_(et.w);
        float4 ct = *(const float4*)(P.chist + (s + 1) * C + 4 * lane);
        cd[s].x = fmaxf(ct.x, 0.f) * MSCALE;
        cd[s].y = fmaxf(ct.y, 0.f) * MSCALE;
        cd[s].z = fmaxf(ct.z, 0.f) * MSCALE;
        cd[s].w = fmaxf(ct.w, 0.f) * MSCALE;
        inv_s[s] = 1.0f / P.ssum4[s + 1];
    }

    float4 acc = make_float4(0.f, 0.f, 0.f, 0.f);
    float sumloc = 0.f;
    const int stride = GRID_BIG * 8;

    for (int i = blockIdx.x * 8 + rg; i < N_LOC; i += stride) {
        float4 m, a4 = make_float4(0.f, 0.f, 0.f, 0.f);
        if (CONVERT) {
            float4 mf = *(const float4*)(P.mem0 + (size_t)i * C + 4 * lane);
            m.x = mf.x * MSCALE; m.y = mf.y * MSCALE;
            m.z = mf.z * MSCALE; m.w = mf.w * MSCALE;
            *(unsigned*)(P.memq + (size_t)i * C + 4 * lane) = pack_fp8x4(m);
            if (lane < 6) {
                a4 = *(const float4*)(P.addr + (size_t)i * A + 4 * lane);
                ushort4 au; au.x = f2bf(a4.x); au.y = f2bf(a4.y);
                au.z = f2bf(a4.z); au.w = f2bf(a4.w);
                *(ushort4*)(P.addrbf + (size_t)i * A + 4 * lane) = au;
            }
        } else {
            unsigned mw = *(const unsigned*)(P.memq + (size_t)i * C + 4 * lane);
            m = unpack_fp8x4(mw);
            if (lane < 6) {
                ushort4 au = *(const ushort4*)(P.addrbf + (size_t)i * A + 4 * lane);
                a4 = make_float4(bf2f(au.x), bf2f(au.y), bf2f(au.z), bf2f(au.w));
            }
        }

#pragma unroll
        for (int s = 0; s < NPREV; ++s) {
            float w = P.e[s * N_LOC + i] * inv_s[s];
            m.x = m.x * (1.f - w * er[s].x) + w * cd[s].x;
            m.y = m.y * (1.f - w * er[s].y) + w * cd[s].y;
            m.z = m.z * (1.f - w * er[s].z) + w * cd[s].z;
            m.w = m.w * (1.f - w * er[s].w) + w * cd[s].w;
        }

        float sv = m.x * qc.x + m.y * qc.y + m.z * qc.z + m.w * qc.w;
        sv += a4.x * qa.x + a4.y * qa.y + a4.z * qa.z + a4.w * qa.w;
        sv += __shfl_xor(sv, 1);
        sv += __shfl_xor(sv, 2);
        sv += __shfl_xor(sv, 4);
        sv += __shfl_xor(sv, 8);
        sv += __shfl_xor(sv, 16);
        float ev = __expf(beta * sv);
        if (WRITE_E && lane == 0) enew[i] = ev;
        if (lane == 0) sumloc += ev;
        acc.x += ev * m.x; acc.y += ev * m.y;
        acc.z += ev * m.z; acc.w += ev * m.w;
    }

    *(float4*)(&sc[rg][4 * lane]) = acc;
    ssum[threadIdx.x] = sumloc;
    __syncthreads();
    if (threadIdx.x < C) {
        float v = 0.f;
#pragma unroll
        for (int g = 0; g < 8; ++g) v += sc[g][threadIdx.x];
        atomicAdd(P.craw + threadIdx.x, v);
    }
    for (int off = 128; off > 0; off >>= 1) {
        if (threadIdx.x < off) ssum[threadIdx.x] += ssum[threadIdx.x + off];
        __syncthreads();
    }
    if (threadIdx.x == 0) atomicAdd(P.craw + C, ssum[0]);
}

// ---------------------------------------------------------------------------
// Projection phase: blocks 0..127, 2 k-rows each. q/sharpen into qacc; if
// doEC, erase/cand h-parts into eslot/cslot (biases pre-seeded by the GRU).
// ---------------------------------------------------------------------------
__device__ void proj_phase(const Params& P, const float* __restrict__ h,
                           float* __restrict__ eslot, float* __restrict__ cslot,
                           bool doEC, bool addQBias)
{
    const int tid = threadIdx.x;
    const int bid = blockIdx.x;        // < 128
    const int k0 = bid * 2;
    const float hv0 = h[k0], hv1 = h[k0 + 1];
    if (tid < AC) {
        float a = hv0 * P.W_q[k0 * AC + tid] + hv1 * P.W_q[(k0 + 1) * AC + tid];
        if (addQBias && bid == 0) a += P.b_q[tid];
        atomicAdd(P.qacc + tid, a);
    } else if (tid == AC) {
        float a = hv0 * P.u_sh[k0] + hv1 * P.u_sh[k0 + 1];
        if (addQBias && bid == 0) a += P.b_sh[0];
        atomicAdd(P.qacc + AC, a);
    }
    if (doEC && tid < C) {
        float ev = hv0 * P.W_er[k0 * C + tid] + hv1 * P.W_er[(k0 + 1) * C + tid];
        float cv = hv0 * P.W_ch[k0 * C + tid] + hv1 * P.W_ch[(k0 + 1) * C + tid];
        atomicAdd(eslot + tid, ev);
        atomicAdd(cslot + tid, cv);
    }
}

// ---------------------------------------------------------------------------
// x projections (once): blocks mapped 0..63, 2 k-rows each.
// ---------------------------------------------------------------------------
__device__ void prex_phase(const Params& P, int pb)
{
    const int tid = threadIdx.x;
    const int k0 = pb * 2;
    const float x0 = P.x[k0], x1 = P.x[k0 + 1];
    const float* r0 = P.W_ih + (size_t)k0 * G3;
    const float* r1 = P.W_ih + (size_t)(k0 + 1) * G3;
    float g0 = x0 * r0[tid]       + x1 * r1[tid];
    float g1 = x0 * r0[256 + tid] + x1 * r1[256 + tid];
    float g2 = x0 * r0[512 + tid] + x1 * r1[512 + tid];
    if (pb == 0) { g0 += P.b_ih[tid]; g1 += P.b_ih[256 + tid]; g2 += P.b_ih[512 + tid]; }
    atomicAdd(P.gix + tid, g0);
    atomicAdd(P.gix + 256 + tid, g1);
    atomicAdd(P.gix + 512 + tid, g2);
    if (tid < C)
        atomicAdd(P.candx + tid, x0 * P.W_cx[k0 * C + tid] + x1 * P.W_cx[(k0 + 1) * C + tid]);
}

// ---------------------------------------------------------------------------
// Gates phase: 96 blocks (32 content-gi, 64 h-gh) atomically accumulate into
// gacc; last-arriving block applies the GRU, writes h, and preps next step
// (stores ssum4, seeds biases for slot `step`, zeroes craw/gacc/counter).
// ---------------------------------------------------------------------------
__device__ void gates_phase(const Params& P, const float* __restrict__ hprev, int step)
{
    const int tid = threadIdx.x;
    const int bid = blockIdx.x;
    if (bid < 96) {
        if (bid < 32) {
            const float inv = MINV / P.craw[C];
            float g0 = 0.f, g1 = 0.f, g2 = 0.f;
            const int k0 = bid * 4;
            for (int k = k0; k < k0 + 4; ++k) {
                float ck = P.craw[k] * inv;
                const float* row = P.W_ih + (size_t)(X + k) * G3;
                g0 += ck * row[tid]; g1 += ck * row[256 + tid]; g2 += ck * row[512 + tid];
            }
            atomicAdd(P.gacc + tid, g0);
            atomicAdd(P.gacc + 256 + tid, g1);
            atomicAdd(P.gacc + 512 + tid, g2);
        } else {
            float g0 = 0.f, g1 = 0.f, g2 = 0.f;
            const int k0 = (bid - 32) * 4;
            for (int k = k0; k < k0 + 4; ++k) {
                float hk = hprev[k];
                const float* row = P.W_hh + (size_t)k * G3;
                g0 += hk * row[tid]; g1 += hk * row[256 + tid]; g2 += hk * row[512 + tid];
            }
            atomicAdd(P.gacc + 768 + tid, g0);
            atomicAdd(P.gacc + 1024 + tid, g1);
            atomicAdd(P.gacc + 1280 + tid, g2);
        }
        __threadfence();
        __syncthreads();
        __shared__ int lastBlk;
        if (tid == 0) lastBlk = (atomicAdd(P.counter, 1u) == 95u) ? 1 : 0;
        __syncthreads();
        if (lastBlk) {
            __threadfence();
            float ir  = P.gacc[tid]        + P.gix[tid];
            float iz  = P.gacc[256 + tid]  + P.gix[256 + tid];
            float in_ = P.gacc[512 + tid]  + P.gix[512 + tid];
            float hr  = P.gacc[768 + tid]  + P.b_hh[tid];
            float hz  = P.gacc[1024 + tid] + P.b_hh[256 + tid];
            float hn  = P.gacc[1280 + tid] + P.b_hh[512 + tid];
            float r = sigmoidf_(ir + hr);
            float z = sigmoidf_(iz + hz);
            float n = tanhf(in_ + r * hn);
            float h = (1.f - z) * n + z * hprev[tid];
            if (step == 4) P.hout[tid] = h; else P.hbuf[tid] = h;
            if (tid == 0) P.ssum4[step] = P.craw[C];
            if (step < 4) {
                // seed biases for the projections computed from h_step (slot = step)
                if (tid < AC)       P.qacc[tid] = P.b_q[tid];
                else if (tid == AC) P.qacc[AC]  = P.b_sh[0];
                else if (tid < 160) P.qacc[tid] = 0.f;
                if (tid < C) {
                    P.ehist[step * C + tid] = P.b_er[tid];
                    P.chist[step * C + tid] = P.candx[tid] + P.b_cd[tid];
                }
                if (tid < 132) P.craw[tid] = 0.f;
                for (int j = tid; j < 1536; j += 256) P.gacc[j] = 0.f;
                if (tid == 0) *P.counter = 0u;
            }
            __threadfence();
        }
    }
}

// ---------------------------------------------------------------------------
// The persistent cooperative kernel: everything, 11 grid syncs.
// ---------------------------------------------------------------------------
__global__ void __launch_bounds__(256, 4) mega(Params P)
{
    cg::grid_group grid = cg::this_grid();
    __shared__ float sc[8][C];
    __shared__ float ssum[256];
    const int bid = blockIdx.x;

    // P0: query/sharpen from h0 (blocks 0-127) || x projections (blocks 128-191)
    if (bid < 128)       proj_phase(P, P.h0, nullptr, nullptr, false, true);
    else if (bid < 192)  prex_phase(P, bid - 128);
    __threadfence(); grid.sync();

    // ---- step 1 ----
    big_body<0, true, true>(P, P.e, sc, ssum);
    __threadfence(); grid.sync();
    gates_phase(P, P.h0, 1);
    __threadfence(); grid.sync();
    if (bid < 128) proj_phase(P, P.hbuf, P.ehist + 1 * C, P.chist + 1 * C, true, false);
    __threadfence(); grid.sync();
    // ---- step 2 ----
    big_body<1, true, false>(P, P.e + N_LOC, sc, ssum);
    __threadfence(); grid.sync();
    gates_phase(P, P.hbuf, 2);
    __threadfence(); grid.sync();
    if (bid < 128) proj_phase(P, P.hbuf, P.ehist + 2 * C, P.chist + 2 * C, true, false);
    __threadfence(); grid.sync();
    // ---- step 3 ----
    big_body<2, true, false>(P, P.e + 2 * N_LOC, sc, ssum);
    __threadfence(); grid.sync();
    gates_phase(P, P.hbuf, 3);
    __threadfence(); grid.sync();
    if (bid < 128) proj_phase(P, P.hbuf, P.ehist + 3 * C, P.chist + 3 * C, true, false);
    __threadfence(); grid.sync();
    // ---- step 4 ----
    big_body<3, false, false>(P, P.e, sc, ssum);
    __threadfence(); grid.sync();
    gates_phase(P, P.hbuf, 4);
}

// ===========================================================================
// FALLBACK: proven round-2 multi-dispatch chain (used only if the cooperative
// launch is rejected by the runtime/capture).
// ===========================================================================
template <int NPREV, bool WRITE_E, bool CONVERT>
__global__ __launch_bounds__(256) void big_pass_fb(
    const float* __restrict__ mem0, const float* __restrict__ addr,
    uchar_t* __restrict__ memq, ushort_t* __restrict__ addrbf,
    const float* __restrict__ qacc, const float* __restrict__ ehist,
    const float* __restrict__ chist, const float* __restrict__ ssum4,
    const float* __restrict__ earr, float* __restrict__ enew,
    float* __restrict__ part)
{
    const int lane = threadIdx.x & 31;
    const int rg   = threadIdx.x >> 5;
    float4 qc = *(const float4*)(qacc + A + 4 * lane);
    qc.x *= MINV; qc.y *= MINV; qc.z *= MINV; qc.w *= MINV;
    float4 qa = make_float4(0.f, 0.f, 0.f, 0.f);
    if (lane < 6) qa = *(const float4*)(qacc + 4 * lane);
    float beta;
    { float t = qacc[AC]; beta = (t > 20.f ? t : log1pf(__expf(t))) + 1.0f; }
    constexpr int NP = (NPREV > 0) ? NPREV : 1;
    float4 er[NP], cd[NP];
    float inv_s[NP];
#pragma unroll
    for (int s = 0; s < NPREV; ++s) {
        float4 et = *(const float4*)(ehist + (s + 1) * C + 4 * lane);
        er[s].x = sigmoidf_(et.x); er[s].y = sigmoidf_(et.y);
        er[s].z = sigmoidf_(et.z); er[s].w = sigmoidf_(et.w);
        float4 ct = *(const float4*)(chist + (s + 1) * C + 4 * lane);
        cd[s].x = fmaxf(ct.x, 0.f) * MSCALE; cd[s].y = fmaxf(ct.y, 0.f) * MSCALE;
        cd[s].z = fmaxf(ct.z, 0.f) * MSCALE; cd[s].w = fmaxf(ct.w, 0.f) * MSCALE;
        inv_s[s] = 1.0f / ssum4[s + 1];
    }
    float4 acc = make_float4(0.f, 0.f, 0.f, 0.f);
    float sumloc = 0.f;
    const int stride = gridDim.x * 8;
    for (int i = blockIdx.x * 8 + rg; i < N_LOC; i += stride) {
        float4 m, a4 = make_float4(0.f, 0.f, 0.f, 0.f);
        if (CONVERT) {
            float4 mf = *(const float4*)(mem0 + (size_t)i * C + 4 * lane);
            m.x = mf.x * MSCALE; m.y = mf.y * MSCALE;
            m.z = mf.z * MSCALE; m.w = mf.w * MSCALE;
            *(unsigned*)(memq + (size_t)i * C + 4 * lane) = pack_fp8x4(m);
            if (lane < 6) {
                a4 = *(const float4*)(addr + (size_t)i * A + 4 * lane);
                ushort4 au; au.x = f2bf(a4.x); au.y = f2bf(a4.y);
                au.z = f2bf(a4.z); au.w = f2bf(a4.w);
                *(ushort4*)(addrbf + (size_t)i * A + 4 * lane) = au;
            }
        } else {
            unsigned mw = *(const unsigned*)(memq + (size_t)i * C + 4 * lane);
            m = unpack_fp8x4(mw);
            if (lane < 6) {
                ushort4 au = *(const ushort4*)(addrbf + (size_t)i * A + 4 * lane);
                a4 = make_float4(bf2f(au.x), bf2f(au.y), bf2f(au.z), bf2f(au.w));
            }
        }
#pragma unroll
        for (int s = 0; s < NPREV; ++s) {
            float w = earr[s * N_LOC + i] * inv_s[s];
            m.x = m.x * (1.f - w * er[s].x) + w * cd[s].x;
            m.y = m.y * (1.f - w * er[s].y) + w * cd[s].y;
            m.z = m.z * (1.f - w * er[s].z) + w * cd[s].z;
            m.w = m.w * (1.f - w * er[s].w) + w * cd[s].w;
        }
        float sv = m.x * qc.x + m.y * qc.y + m.z * qc.z + m.w * qc.w;
        sv += a4.x * qa.x + a4.y * qa.y + a4.z * qa.z + a4.w * qa.w;
        sv += __shfl_xor(sv, 1); sv += __shfl_xor(sv, 2); sv += __shfl_xor(sv, 4);
        sv += __shfl_xor(sv, 8); sv += __shfl_xor(sv, 16);
        float ev = __expf(beta * sv);
        if (WRITE_E && lane == 0) enew[i] = ev;
        if (lane == 0) sumloc += ev;
        acc.x += ev * m.x; acc.y += ev * m.y;
        acc.z += ev * m.z; acc.w += ev * m.w;
    }
    __shared__ float sc[8][C];
    __shared__ float ssum[256];
    *(float4*)(&sc[rg][4 * lane]) = acc;
    ssum[threadIdx.x] = sumloc;
    __syncthreads();
    if (threadIdx.x < C) {
        float v = 0.f;
#pragma unroll
        for (int g = 0; g < 8; ++g) v += sc[g][threadIdx.x];
        part[(size_t)threadIdx.x * GRID_BIG + blockIdx.x] = v;
    }
    for (int off = 128; off > 0; off >>= 1) {
        if (threadIdx.x < off) ssum[threadIdx.x] += ssum[threadIdx.x + off];
        __syncthreads();
    }
    if (threadIdx.x == 0) part[(size_t)C * GRID_BIG + blockIdx.x] = ssum[0];
}

__global__ __launch_bounds__(256) void reduce_part(
    const float* __restrict__ part, float* __restrict__ craw,
    float* __restrict__ ssum4, int step)
{
    const int j = blockIdx.x;
    float v = 0.f;
    for (int b = threadIdx.x; b < GRID_BIG; b += 256)
        v += part[(size_t)j * GRID_BIG + b];
    __shared__ float sh[256];
    sh[threadIdx.x] = v;
    __syncthreads();
    for (int off = 128; off > 0; off >>= 1) {
        if (threadIdx.x < off) sh[threadIdx.x] += sh[threadIdx.x + off];
        __syncthreads();
    }
    if (threadIdx.x == 0) {
        craw[j] = sh[0];
        if (j == C) ssum4[step] = sh[0];
    }
}

__global__ __launch_bounds__(256) void prex(
    const float* __restrict__ x, const float* __restrict__ W_ih,
    const float* __restrict__ b_ih, const float* __restrict__ W_cx,
    float* __restrict__ gix, float* __restrict__ candx)
{
    const int tid = threadIdx.x;
    float a0 = 0.f, a1 = 0.f, a2 = 0.f, ac = 0.f;
    const int k0 = blockIdx.x * 8;
    for (int k = k0; k < k0 + 8; ++k) {
        float xk = x[k];
        const float* row = W_ih + (size_t)k * G3;
        a0 += xk * row[tid]; a1 += xk * row[256 + tid]; a2 += xk * row[512 + tid];
        if (tid < C) ac += xk * W_cx[k * C + tid];
    }
    const bool b0 = (blockIdx.x == 0);
    atomicAdd(gix + tid,       a0 + (b0 ? b_ih[tid] : 0.f));
    atomicAdd(gix + 256 + tid, a1 + (b0 ? b_ih[256 + tid] : 0.f));
    atomicAdd(gix + 512 + tid, a2 + (b0 ? b_ih[512 + tid] : 0.f));
    if (tid < C) atomicAdd(candx + tid, ac);
}

__global__ __launch_bounds__(256) void post(
    const float* __restrict__ h,
    const float* __restrict__ W_er, const float* __restrict__ b_er,
    const float* __restrict__ W_ch, const float* __restrict__ b_cd,
    const float* __restrict__ W_q,  const float* __restrict__ b_q,
    const float* __restrict__ u_sh, const float* __restrict__ b_sh,
    const float* __restrict__ candx,
    float* __restrict__ eslot, float* __restrict__ cslot,
    float* __restrict__ qacc)
{
    const int tid = threadIdx.x;
    float ae = 0.f, ac = 0.f, aq = 0.f, ab = 0.f;
    const int k0 = blockIdx.x * 16;
    for (int k = k0; k < k0 + 16; ++k) {
        float hk = h[k];
        if (tid < C)  { ae += hk * W_er[k * C + tid]; ac += hk * W_ch[k * C + tid]; }
        if (tid < AC)   aq += hk * W_q[k * AC + tid];
        if (tid == 255) ab += hk * u_sh[k];
    }
    const bool b0 = (blockIdx.x == 0);
    if (tid < C) {
        atomicAdd(eslot + tid, ae + (b0 ? b_er[tid] : 0.f));
        atomicAdd(cslot + tid, ac + (b0 ? (candx[tid] + b_cd[tid]) : 0.f));
    }
    if (tid < AC)   atomicAdd(qacc + tid, aq + (b0 ? b_q[tid] : 0.f));
    if (tid == 255) atomicAdd(qacc + AC, ab + (b0 ? b_sh[0] : 0.f));
}

__global__ __launch_bounds__(256) void gatesfin(
    const float* __restrict__ craw, const float* __restrict__ hprev,
    const float* __restrict__ W_ih, const float* __restrict__ W_hh,
    const float* __restrict__ b_hh, const float* __restrict__ gix,
    float* __restrict__ p2, float* __restrict__ hout,
    float* __restrict__ qacc, unsigned* __restrict__ counter)
{
    const int tid = threadIdx.x;
    const float inv = MINV / craw[C];
    float gi0 = 0.f, gi1 = 0.f, gi2 = 0.f, gh0 = 0.f, gh1 = 0.f, gh2 = 0.f;
    const int kc0 = blockIdx.x * 8;
    for (int k = kc0; k < kc0 + 8; ++k) {
        float ck = craw[k] * inv;
        const float* row = W_ih + (size_t)(X + k) * G3;
        gi0 += ck * row[tid]; gi1 += ck * row[256 + tid]; gi2 += ck * row[512 + tid];
    }
    const int kh0 = blockIdx.x * 16;
    for (int k = kh0; k < kh0 + 16; ++k) {
        float hk = hprev[k];
        const float* row = W_hh + (size_t)k * G3;
        gh0 += hk * row[tid]; gh1 += hk * row[256 + tid]; gh2 += hk * row[512 + tid];
    }
    const bool b0 = (blockIdx.x == 0);
    float* pb = p2 + blockIdx.x * 1536;
    pb[tid]        = gi0 + (b0 ? gix[tid] : 0.f);
    pb[256 + tid]  = gi1 + (b0 ? gix[256 + tid] : 0.f);
    pb[512 + tid]  = gi2 + (b0 ? gix[512 + tid] : 0.f);
    pb[768 + tid]  = gh0 + (b0 ? b_hh[tid] : 0.f);
    pb[1024 + tid] = gh1 + (b0 ? b_hh[256 + tid] : 0.f);
    pb[1280 + tid] = gh2 + (b0 ? b_hh[512 + tid] : 0.f);
    __threadfence();
    __syncthreads();
    __shared__ int lastBlk;
    if (tid == 0) lastBlk = (atomicAdd(counter, 1u) == 15u) ? 1 : 0;
    __syncthreads();
    if (!lastBlk) return;
    __threadfence();
    float ir = 0.f, iz = 0.f, in_ = 0.f, hr = 0.f, hz = 0.f, hn = 0.f;
    for (int b = 0; b < 16; ++b) {
        const float* q = p2 + b * 1536;
        ir += q[tid]; iz += q[256 + tid]; in_ += q[512 + tid];
        hr += q[768 + tid]; hz += q[1024 + tid]; hn += q[1280 + tid];
    }
    float r = sigmoidf_(ir + hr);
    float z = sigmoidf_(iz + hz);
    float n = tanhf(in_ + r * hn);
    hout[tid] = (1.f - z) * n + z * hprev[tid];
    if (tid < 160) qacc[tid] = 0.f;
    if (tid == 0) *counter = 0u;
}

extern "C" void kernel_launch(void* const* d_in, const int* in_sizes, int n_in,
                              void* d_out, int out_size, void* d_ws, size_t ws_size,
                              hipStream_t stream) {
    (void)in_sizes; (void)n_in; (void)out_size; (void)ws_size;
    const float* x    = (const float*)d_in[0];
    const float* h0   = (const float*)d_in[1];
    const float* mem0 = (const float*)d_in[2];
    const float* addr = (const float*)d_in[3];
    const float* W_q  = (const float*)d_in[4];
    const float* b_q  = (const float*)d_in[5];
    const float* u_sh = (const float*)d_in[6];
    const float* b_sh = (const float*)d_in[7];
    const float* W_er = (const float*)d_in[8];
    const float* b_er = (const float*)d_in[9];
    const float* W_ch = (const float*)d_in[10];
    const float* W_cx = (const float*)d_in[11];
    const float* b_cd = (const float*)d_in[12];
    const float* W_ih = (const float*)d_in[13];
    const float* W_hh = (const float*)d_in[14];
    const float* b_ih = (const float*)d_in[15];
    const float* b_hh = (const float*)d_in[16];
    float* hout = (float*)d_out;

    // workspace layout
    float*    e      = (float*)d_ws;                           // [3][N_LOC]
    uchar_t*  memq   = (uchar_t*)(e + 3 * N_LOC);              // [N_LOC][C] fp8
    ushort_t* addrbf = (ushort_t*)(memq + (size_t)N_LOC * C);  // [N_LOC][A] bf16
    float*    S      = (float*)(addrbf + (size_t)N_LOC * A);
    float*    craw   = S;                                      // [132] (+pad to 144)
    float*    qacc   = S + 144;                                // [160]
    float*    ehist  = S + 304;                                // [5][128]
    float*    chist  = S + 944;                                // [5][128]
    float*    gix    = S + 1584;                               // [768]
    float*    candx  = S + 2352;                               // [128]
    float*    ssum4  = S + 2480;                               // [8]
    unsigned* counter= (unsigned*)(S + 2488);                  // [1] (+pad)
    float*    gacc   = S + 2496;                               // [1536]
    float*    hbuf   = S + 4032;                               // [256]
    // zeroed region ends at S+4288
    float*    part   = S + 4352;                               // [132][1024] (fallback)
    float*    p2     = part + 132 * GRID_BIG;                  // [16][1536]  (fallback)

    hipMemsetAsync(S, 0, 4288 * sizeof(float), stream);

    Params Pr;
    Pr.x = x; Pr.h0 = h0; Pr.mem0 = mem0; Pr.addr = addr;
    Pr.W_q = W_q; Pr.b_q = b_q; Pr.u_sh = u_sh; Pr.b_sh = b_sh;
    Pr.W_er = W_er; Pr.b_er = b_er; Pr.W_ch = W_ch; Pr.W_cx = W_cx; Pr.b_cd = b_cd;
    Pr.W_ih = W_ih; Pr.W_hh = W_hh; Pr.b_ih = b_ih; Pr.b_hh = b_hh;
    Pr.hout = hout; Pr.e = e; Pr.memq = memq; Pr.addrbf = addrbf;
    Pr.craw = craw; Pr.qacc = qacc; Pr.ehist = ehist; Pr.chist = chist;
    Pr.gix = gix; Pr.candx = candx; Pr.ssum4 = ssum4; Pr.gacc = gacc;
    Pr.hbuf = hbuf; Pr.counter = counter;

    void* kargs[] = { (void*)&Pr };
    hipError_t ce = hipLaunchCooperativeKernel((const void*)mega, dim3(GRID_BIG),
                                               dim3(256), kargs, 0, stream);
    if (ce != hipSuccess) {
        (void)hipGetLastError();
        // proven round-2 chain
        prex<<<16, 256, 0, stream>>>(x, W_ih, b_ih, W_cx, gix, candx);
        post<<<16, 256, 0, stream>>>(h0, W_er, b_er, W_ch, b_cd, W_q, b_q, u_sh, b_sh,
                                     candx, ehist, chist, qacc);
        big_pass_fb<0, true, true><<<GRID_BIG, 256, 0, stream>>>(
            mem0, addr, memq, addrbf, qacc, ehist, chist, ssum4, e, e, part);
        reduce_part<<<129, 256, 0, stream>>>(part, craw, ssum4, 1);
        gatesfin<<<16, 256, 0, stream>>>(craw, h0, W_ih, W_hh, b_hh, gix, p2, hout,
                                         qacc, counter);
        post<<<16, 256, 0, stream>>>(hout, W_er, b_er, W_ch, b_cd, W_q, b_q, u_sh, b_sh,
                                     candx, ehist + C, chist + C, qacc);
        big_pass_fb<1, true, false><<<GRID_BIG, 256, 0, stream>>>(
            mem0, addr, memq, addrbf, qacc, ehist, chist, ssum4, e, e + N_LOC, part);
        reduce_part<<<129, 256, 0, stream>>>(part, craw, ssum4, 2);
        gatesfin<<<16, 256, 0, stream>>>(craw, hout, W_ih, W_hh, b_hh, gix, p2, hout,
                                         qacc, counter);
        post<<<16, 256, 0, stream>>>(hout, W_er, b_er, W_ch, b_cd, W_q, b_q, u_sh, b_sh,
                                     candx, ehist + 2 * C, chist + 2 * C, qacc);
        big_pass_fb<2, true, false><<<GRID_BIG, 256, 0, stream>>>(
            mem0, addr, memq, addrbf, qacc, ehist, chist, ssum4, e, e + 2 * N_LOC, part);
        reduce_part<<<129, 256, 0, stream>>>(part, craw, ssum4, 3);
        gatesfin<<<16, 256, 0, stream>>>(craw, hout, W_ih, W_hh, b_hh, gix, p2, hout,
                                         qacc, counter);
        post<<<16, 256, 0, stream>>>(hout, W_er, b_er, W_ch, b_cd, W_q, b_q, u_sh, b_sh,
                                     candx, ehist + 3 * C, chist + 3 * C, qacc);
        big_pass_fb<3, false, false><<<GRID_BIG, 256, 0, stream>>>(
            mem0, addr, memq, addrbf, qacc, ehist, chist, ssum4, e, e, part);
        reduce_part<<<129, 256, 0, stream>>>(part, craw, ssum4, 4);
        gatesfin<<<16, 256, 0, stream>>>(craw, hout, W_ih, W_hh, b_hh, gix, p2, hout,
                                         qacc, counter);
    }
}

// Round 4
// 717.623 us; speedup vs baseline: 3.6302x; 3.6302x over previous
//
#include <hip/hip_runtime.h>

#define N_LOC 500000
#define C 128
#define A 24
#define AC 152          // A + C
#define H 256
#define X 128
#define G3 768          // 3*H
#define GRID_BIG 1024
#define MSCALE 64.0f    // contents stored as fp8(e4m3) of 64*value (dodges denorm cliff)
#define MINV 0.015625f  // 1/64

typedef unsigned short ushort_t;
typedef unsigned char uchar_t;
typedef float floatx2 __attribute__((ext_vector_type(2)));

__device__ __forceinline__ float sigmoidf_(float x) { return 1.0f / (1.0f + __expf(-x)); }

// bf16 pack/unpack (RNE; inputs finite) -- used for addresses
__device__ __forceinline__ ushort_t f2bf(float f) {
    unsigned u = __float_as_uint(f);
    u += 0x7FFFu + ((u >> 16) & 1u);
    return (ushort_t)(u >> 16);
}
__device__ __forceinline__ float bf2f(ushort_t s) {
    return __uint_as_float(((unsigned)s) << 16);
}

// ---- OCP e4m3fn helpers (HW cvt if available, bit-exact SW fallback) ----
#if defined(__has_builtin)
#if __has_builtin(__builtin_amdgcn_cvt_pk_fp8_f32) && __has_builtin(__builtin_amdgcn_cvt_pk_f32_fp8)
#define HAVE_HW_FP8 1
#endif
#endif

__device__ __forceinline__ unsigned f2fp8_sw(float f) {
    unsigned sgn = (__float_as_uint(f) >> 24) & 0x80u;
    float af = fminf(fabsf(f), 448.0f);
    unsigned q;
    if (af < 0.015625f) {
        q = (unsigned)__float2int_rn(af * 512.0f);
    } else {
        unsigned a = __float_as_uint(af);
        a += 0x7FFFFu + ((a >> 20) & 1u);
        unsigned e = (a >> 23) - 120u;
        q = (e << 3) | ((a >> 20) & 7u);
        if (q > 126u) q = 126u;
    }
    return q | sgn;
}
__device__ __forceinline__ float fp8d_sw(unsigned b) {
    unsigned sgn = (b & 0x80u) << 24;
    unsigned e = (b >> 3) & 15u;
    unsigned m = b & 7u;
    float fn = __uint_as_float(sgn | ((e + 120u) << 23) | (m << 20));
    float fd = __uint_as_float(sgn | __float_as_uint((float)m * 0.001953125f));
    return e ? fn : fd;
}
__device__ __forceinline__ unsigned pack_fp8x4(float4 m) {
#ifdef HAVE_HW_FP8
    int w = 0;
    w = __builtin_amdgcn_cvt_pk_fp8_f32(m.x, m.y, w, false);
    w = __builtin_amdgcn_cvt_pk_fp8_f32(m.z, m.w, w, true);
    return (unsigned)w;
#else
    return f2fp8_sw(m.x) | (f2fp8_sw(m.y) << 8) | (f2fp8_sw(m.z) << 16) | (f2fp8_sw(m.w) << 24);
#endif
}
__device__ __forceinline__ float4 unpack_fp8x4(unsigned w) {
#ifdef HAVE_HW_FP8
    floatx2 lo = __builtin_amdgcn_cvt_pk_f32_fp8((int)w, false);
    floatx2 hi = __builtin_amdgcn_cvt_pk_f32_fp8((int)w, true);
    return make_float4(lo[0], lo[1], hi[0], hi[1]);
#else
    return make_float4(fp8d_sw(w & 255u), fp8d_sw((w >> 8) & 255u),
                       fp8d_sw((w >> 16) & 255u), fp8d_sw(w >> 24));
#endif
}

// ---------------------------------------------------------------------------
// Big streaming pass over N_LOC x C memory. Contents cached as fp8 (x64
// scaled), addresses as bf16. Block epilogue atomicAdds its column partials
// into craw8s[8][132] (shadow = blockIdx&7, col 128 = softmax denominator),
// replacing the separate reduce_part dispatch. Content cols in x64 domain.
// ---------------------------------------------------------------------------
template <int NPREV, bool WRITE_E, bool CONVERT>
__global__ __launch_bounds__(256) void big_pass(
    const float* __restrict__ mem0, const float* __restrict__ addr,
    uchar_t* __restrict__ memq, ushort_t* __restrict__ addrbf,
    const float* __restrict__ qacc,   // [153]: q[0..151], raw sharpen at [152]
    const float* __restrict__ ehist,  // [5][128] raw erase pre-sigmoid
    const float* __restrict__ chist,  // [5][128] raw cand pre-relu
    const float* __restrict__ ssum4,  // [8]: softmax denom of step s
    const float* __restrict__ earr,   // [3][N_LOC] raw exp values per step
    float* __restrict__ enew,         // e output for this step (if WRITE_E)
    float* __restrict__ craw8s)       // [8][132] shadowed atomic accumulators
{
    const int lane = threadIdx.x & 31;   // column group: 4 elements each
    const int rg   = threadIdx.x >> 5;   // row group 0..7

    float4 qc = *(const float4*)(qacc + A + 4 * lane);
    qc.x *= MINV; qc.y *= MINV; qc.z *= MINV; qc.w *= MINV;  // fold 1/64 (m is x64)
    float4 qa = make_float4(0.f, 0.f, 0.f, 0.f);
    if (lane < 6) qa = *(const float4*)(qacc + 4 * lane);
    float beta;
    { float t = qacc[AC]; beta = (t > 20.f ? t : log1pf(__expf(t))) + 1.0f; }

    constexpr int NP = (NPREV > 0) ? NPREV : 1;
    float4 er[NP], cd[NP];
    float inv_s[NP];
#pragma unroll
    for (int s = 0; s < NPREV; ++s) {
        float4 et = *(const float4*)(ehist + (s + 1) * C + 4 * lane);
        er[s].x = sigmoidf_(et.x); er[s].y = sigmoidf_(et.y);
        er[s].z = sigmoidf_(et.z); er[s].w = sigmoidf_(et.w);
        float4 ct = *(const float4*)(chist + (s + 1) * C + 4 * lane);
        cd[s].x = fmaxf(ct.x, 0.f) * MSCALE;
        cd[s].y = fmaxf(ct.y, 0.f) * MSCALE;
        cd[s].z = fmaxf(ct.z, 0.f) * MSCALE;
        cd[s].w = fmaxf(ct.w, 0.f) * MSCALE;
        inv_s[s] = 1.0f / ssum4[s + 1];
    }

    float4 acc = make_float4(0.f, 0.f, 0.f, 0.f);
    float sumloc = 0.f;
    const int stride = GRID_BIG * 8;

    for (int i = blockIdx.x * 8 + rg; i < N_LOC; i += stride) {
        float4 m, a4 = make_float4(0.f, 0.f, 0.f, 0.f);
        if (CONVERT) {
            float4 mf = *(const float4*)(mem0 + (size_t)i * C + 4 * lane);
            m.x = mf.x * MSCALE; m.y = mf.y * MSCALE;
            m.z = mf.z * MSCALE; m.w = mf.w * MSCALE;
            *(unsigned*)(memq + (size_t)i * C + 4 * lane) = pack_fp8x4(m);
            if (lane < 6) {
                a4 = *(const float4*)(addr + (size_t)i * A + 4 * lane);
                ushort4 au; au.x = f2bf(a4.x); au.y = f2bf(a4.y);
                au.z = f2bf(a4.z); au.w = f2bf(a4.w);
                *(ushort4*)(addrbf + (size_t)i * A + 4 * lane) = au;
            }
        } else {
            unsigned mw = *(const unsigned*)(memq + (size_t)i * C + 4 * lane);
            m = unpack_fp8x4(mw);  // scaled domain (64x)
            if (lane < 6) {
                ushort4 au = *(const ushort4*)(addrbf + (size_t)i * A + 4 * lane);
                a4 = make_float4(bf2f(au.x), bf2f(au.y), bf2f(au.z), bf2f(au.w));
            }
        }

#pragma unroll
        for (int s = 0; s < NPREV; ++s) {
            float w = earr[s * N_LOC + i] * inv_s[s];
            m.x = m.x * (1.f - w * er[s].x) + w * cd[s].x;
            m.y = m.y * (1.f - w * er[s].y) + w * cd[s].y;
            m.z = m.z * (1.f - w * er[s].z) + w * cd[s].z;
            m.w = m.w * (1.f - w * er[s].w) + w * cd[s].w;
        }

        float sv = m.x * qc.x + m.y * qc.y + m.z * qc.z + m.w * qc.w;
        sv += a4.x * qa.x + a4.y * qa.y + a4.z * qa.z + a4.w * qa.w;
        sv += __shfl_xor(sv, 1);
        sv += __shfl_xor(sv, 2);
        sv += __shfl_xor(sv, 4);
        sv += __shfl_xor(sv, 8);
        sv += __shfl_xor(sv, 16);
        float ev = __expf(beta * sv);
        if (WRITE_E && lane == 0) enew[i] = ev;
        if (lane == 0) sumloc += ev;
        acc.x += ev * m.x; acc.y += ev * m.y;
        acc.z += ev * m.z; acc.w += ev * m.w;
    }

    __shared__ float sc[8][C];
    __shared__ float ssum[256];
    *(float4*)(&sc[rg][4 * lane]) = acc;
    ssum[threadIdx.x] = sumloc;
    __syncthreads();
    float* shadow = craw8s + (blockIdx.x & 7) * 132;
    if (threadIdx.x < C) {
        float v = 0.f;
#pragma unroll
        for (int g = 0; g < 8; ++g) v += sc[g][threadIdx.x];
        atomicAdd(shadow + threadIdx.x, v);
    }
    for (int off = 128; off > 0; off >>= 1) {
        if (threadIdx.x < off) ssum[threadIdx.x] += ssum[threadIdx.x + off];
        __syncthreads();
    }
    if (threadIdx.x == 0) atomicAdd(shadow + C, ssum[0]);
}

// ---------------------------------------------------------------------------
// Once per launch (32 blocks): blocks 0-15 x-projections (gix, candx);
// blocks 16-31 step-1 query/sharpen from h0 into qacc slot 1.
// ---------------------------------------------------------------------------
__global__ __launch_bounds__(256) void init_k(
    const float* __restrict__ x, const float* __restrict__ h0,
    const float* __restrict__ W_ih, const float* __restrict__ b_ih,
    const float* __restrict__ W_cx,
    const float* __restrict__ W_q,  const float* __restrict__ b_q,
    const float* __restrict__ u_sh, const float* __restrict__ b_sh,
    float* __restrict__ gix, float* __restrict__ candx,
    float* __restrict__ q1)
{
    const int tid = threadIdx.x;
    const int bid = blockIdx.x;
    if (bid < 16) {
        float a0 = 0.f, a1 = 0.f, a2 = 0.f, ac = 0.f;
        const int k0 = bid * 8;
        for (int k = k0; k < k0 + 8; ++k) {
            float xk = x[k];
            const float* row = W_ih + (size_t)k * G3;
            a0 += xk * row[tid]; a1 += xk * row[256 + tid]; a2 += xk * row[512 + tid];
            if (tid < C) ac += xk * W_cx[k * C + tid];
        }
        const bool b0 = (bid == 0);
        atomicAdd(gix + tid,       a0 + (b0 ? b_ih[tid] : 0.f));
        atomicAdd(gix + 256 + tid, a1 + (b0 ? b_ih[256 + tid] : 0.f));
        atomicAdd(gix + 512 + tid, a2 + (b0 ? b_ih[512 + tid] : 0.f));
        if (tid < C) atomicAdd(candx + tid, ac);
    } else {
        const int k0 = (bid - 16) * 16;
        float aq = 0.f, ab = 0.f;
        for (int k = k0; k < k0 + 16; ++k) {
            float hk = h0[k];
            if (tid < AC)   aq += hk * W_q[(size_t)k * AC + tid];
            if (tid == AC)  ab += hk * u_sh[k];
        }
        const bool b0 = (bid == 16);
        if (tid < AC)  atomicAdd(q1 + tid, aq + (b0 ? b_q[tid] : 0.f));
        if (tid == AC) atomicAdd(q1 + AC, ab + (b0 ? b_sh[0] : 0.f));
    }
}

// ---------------------------------------------------------------------------
// Per-step tail (160 blocks; 96 for step 4):
//  blocks  0..31 : content-gi partials (4 rows of W_ih[X+k]) -> gacc[0..767]
//  blocks 32..95 : h-gh partials (4 rows of W_hh)            -> gacc[768..1535]
//  last of 96    : GRU combine -> h (hbuf/hout), ssum4[step], seed next-step
//                  bias slots, release flag.
//  blocks 96..159: prefetch W rows to regs, spin on flag (producers never
//                  wait on consumers => deadlock-free), then q/erase/cand
//                  projections from h into next-step slots.
// ---------------------------------------------------------------------------
__global__ __launch_bounds__(256) void tail(
    const float* __restrict__ craw8s,   // [8][132] this step
    const float* __restrict__ hprev,
    const float* __restrict__ W_ih, const float* __restrict__ W_hh,
    const float* __restrict__ b_hh, const float* __restrict__ gix,
    float* __restrict__ gaccs,          // [1536] this step
    float* __restrict__ hbuf, float* __restrict__ hout,
    float* __restrict__ ssum4, int step, int do_proj,
    const float* __restrict__ W_er, const float* __restrict__ b_er,
    const float* __restrict__ W_ch, const float* __restrict__ b_cd,
    const float* __restrict__ W_q,  const float* __restrict__ b_q,
    const float* __restrict__ u_sh, const float* __restrict__ b_sh,
    const float* __restrict__ candx,
    float* __restrict__ eslot, float* __restrict__ cslot,
    float* __restrict__ qnext,
    unsigned* __restrict__ counter, unsigned* __restrict__ flag)
{
    const int tid = threadIdx.x;
    const int bid = blockIdx.x;

    if (bid < 96) {
        if (bid < 32) {
            float denom = 0.f;
#pragma unroll
            for (int m = 0; m < 8; ++m) denom += craw8s[m * 132 + C];
            const float inv = MINV / denom;
            const int k0 = bid * 4;
            float g0 = 0.f, g1 = 0.f, g2 = 0.f;
#pragma unroll
            for (int j = 0; j < 4; ++j) {
                float ck = 0.f;
#pragma unroll
                for (int m = 0; m < 8; ++m) ck += craw8s[m * 132 + k0 + j];
                ck *= inv;
                const float* row = W_ih + (size_t)(X + k0 + j) * G3;
                g0 += ck * row[tid]; g1 += ck * row[256 + tid]; g2 += ck * row[512 + tid];
            }
            atomicAdd(gaccs + tid, g0);
            atomicAdd(gaccs + 256 + tid, g1);
            atomicAdd(gaccs + 512 + tid, g2);
        } else {
            const int k0 = (bid - 32) * 4;
            float g0 = 0.f, g1 = 0.f, g2 = 0.f;
#pragma unroll
            for (int j = 0; j < 4; ++j) {
                float hk = hprev[k0 + j];
                const float* row = W_hh + (size_t)(k0 + j) * G3;
                g0 += hk * row[tid]; g1 += hk * row[256 + tid]; g2 += hk * row[512 + tid];
            }
            atomicAdd(gaccs + 768 + tid, g0);
            atomicAdd(gaccs + 1024 + tid, g1);
            atomicAdd(gaccs + 1280 + tid, g2);
        }
        __threadfence();
        __syncthreads();
        __shared__ int lastBlk;
        if (tid == 0) lastBlk = (atomicAdd(counter, 1u) == 95u) ? 1 : 0;
        __syncthreads();
        if (!lastBlk) return;
        __threadfence();

        // GRU combine
        float ir  = gaccs[tid]        + gix[tid];
        float iz  = gaccs[256 + tid]  + gix[256 + tid];
        float in_ = gaccs[512 + tid]  + gix[512 + tid];
        float hr  = gaccs[768 + tid]  + b_hh[tid];
        float hz  = gaccs[1024 + tid] + b_hh[256 + tid];
        float hn  = gaccs[1280 + tid] + b_hh[512 + tid];
        float r = sigmoidf_(ir + hr);
        float z = sigmoidf_(iz + hz);
        float n = tanhf(in_ + r * hn);
        float h = (1.f - z) * n + z * hprev[tid];
        hbuf[tid] = h;
        if (step == 4) hout[tid] = h;
        if (tid == 0) {
            float denom = 0.f;
#pragma unroll
            for (int m = 0; m < 8; ++m) denom += craw8s[m * 132 + C];
            ssum4[step] = denom;
        }
        if (do_proj) {
            // seed next-step slots with biases; proj blocks add the h-parts
            if (tid < AC)       qnext[tid] = b_q[tid];
            else if (tid == AC) qnext[AC]  = b_sh[0];
            if (tid < C) {
                eslot[tid] = b_er[tid];
                cslot[tid] = candx[tid] + b_cd[tid];
            }
        }
        __threadfence();
        __syncthreads();
        if (do_proj && tid == 0)
            __hip_atomic_store(flag, 1u, __ATOMIC_RELEASE, __HIP_MEMORY_SCOPE_AGENT);
        return;
    }

    if (!do_proj) return;

    // projection blocks: prefetch weights to registers, then wait for h
    const int k0 = (bid - 96) * 4;
    float wq[4], we[4], wc[4], us[4];
    if (tid < AC) {
#pragma unroll
        for (int j = 0; j < 4; ++j) wq[j] = W_q[(size_t)(k0 + j) * AC + tid];
    } else if (tid == AC) {
#pragma unroll
        for (int j = 0; j < 4; ++j) us[j] = u_sh[k0 + j];
    }
    if (tid < C) {
#pragma unroll
        for (int j = 0; j < 4; ++j) {
            we[j] = W_er[(size_t)(k0 + j) * C + tid];
            wc[j] = W_ch[(size_t)(k0 + j) * C + tid];
        }
    }
    if (tid == 0) {
        while (__hip_atomic_load(flag, __ATOMIC_ACQUIRE, __HIP_MEMORY_SCOPE_AGENT) == 0u)
            __builtin_amdgcn_s_sleep(8);
    }
    __syncthreads();
    float hv0 = hbuf[k0], hv1 = hbuf[k0 + 1], hv2 = hbuf[k0 + 2], hv3 = hbuf[k0 + 3];
    if (tid < AC) {
        atomicAdd(qnext + tid, hv0 * wq[0] + hv1 * wq[1] + hv2 * wq[2] + hv3 * wq[3]);
    } else if (tid == AC) {
        atomicAdd(qnext + AC, hv0 * us[0] + hv1 * us[1] + hv2 * us[2] + hv3 * us[3]);
    }
    if (tid < C) {
        atomicAdd(eslot + tid, hv0 * we[0] + hv1 * we[1] + hv2 * we[2] + hv3 * we[3]);
        atomicAdd(cslot + tid, hv0 * wc[0] + hv1 * wc[1] + hv2 * wc[2] + hv3 * wc[3]);
    }
}

extern "C" void kernel_launch(void* const* d_in, const int* in_sizes, int n_in,
                              void* d_out, int out_size, void* d_ws, size_t ws_size,
                              hipStream_t stream) {
    (void)in_sizes; (void)n_in; (void)out_size; (void)ws_size;
    const float* x    = (const float*)d_in[0];
    const float* h0   = (const float*)d_in[1];
    const float* mem0 = (const float*)d_in[2];   // read-only
    const float* addr = (const float*)d_in[3];
    const float* W_q  = (const float*)d_in[4];
    const float* b_q  = (const float*)d_in[5];
    const float* u_sh = (const float*)d_in[6];
    const float* b_sh = (const float*)d_in[7];
    const float* W_er = (const float*)d_in[8];
    const float* b_er = (const float*)d_in[9];
    const float* W_ch = (const float*)d_in[10];
    const float* W_cx = (const float*)d_in[11];
    const float* b_cd = (const float*)d_in[12];
    const float* W_ih = (const float*)d_in[13];
    const float* W_hh = (const float*)d_in[14];
    const float* b_ih = (const float*)d_in[15];
    const float* b_hh = (const float*)d_in[16];
    float* hout = (float*)d_out;

    // workspace layout (~94 MB)
    float*    e      = (float*)d_ws;                           // [3][N_LOC]
    uchar_t*  memq   = (uchar_t*)(e + 3 * N_LOC);              // [N_LOC][C] fp8
    ushort_t* addrbf = (ushort_t*)(memq + (size_t)N_LOC * C);  // [N_LOC][A] bf16
    float*    S      = (float*)(addrbf + (size_t)N_LOC * A);
    float*    craw8  = S;                                      // [4][8][132]
    float*    gacc4  = S + 4224;                               // [4][1536]
    float*    qacc   = S + 10368;                              // [5][160] slot s = query step s
    float*    ehist  = S + 11168;                              // [5][128]
    float*    chist  = S + 11808;                              // [5][128]
    float*    gix    = S + 12448;                              // [768]
    float*    candx  = S + 13216;                              // [128]
    float*    ssum4  = S + 13344;                               // [8]
    float*    hbuf   = S + 13352;                               // [256]
    unsigned* cnt    = (unsigned*)(S + 13608);                  // [4]
    unsigned* flg    = (unsigned*)(S + 13612);                  // [4]
    // zero region: 13616 floats

    hipMemsetAsync(S, 0, 13616 * sizeof(float), stream);
    init_k<<<32, 256, 0, stream>>>(x, h0, W_ih, b_ih, W_cx, W_q, b_q, u_sh, b_sh,
                                   gix, candx, qacc + 160);
    // step 1 (also emits fp8/bf16 copies)
    big_pass<0, true, true><<<GRID_BIG, 256, 0, stream>>>(
        mem0, addr, memq, addrbf, qacc + 160, ehist, chist, ssum4, e, e, craw8);
    tail<<<160, 256, 0, stream>>>(craw8, h0, W_ih, W_hh, b_hh, gix, gacc4,
        hbuf, hout, ssum4, 1, 1, W_er, b_er, W_ch, b_cd, W_q, b_q, u_sh, b_sh,
        candx, ehist + 1 * C, chist + 1 * C, qacc + 2 * 160, cnt + 0, flg + 0);
    // step 2
    big_pass<1, true, false><<<GRID_BIG, 256, 0, stream>>>(
        mem0, addr, memq, addrbf, qacc + 2 * 160, ehist, chist, ssum4, e,
        e + N_LOC, craw8 + 1056);
    tail<<<160, 256, 0, stream>>>(craw8 + 1056, hbuf, W_ih, W_hh, b_hh, gix,
        gacc4 + 1536, hbuf, hout, ssum4, 2, 1, W_er, b_er, W_ch, b_cd, W_q, b_q,
        u_sh, b_sh, candx, ehist + 2 * C, chist + 2 * C, qacc + 3 * 160,
        cnt + 1, flg + 1);
    // step 3
    big_pass<2, true, false><<<GRID_BIG, 256, 0, stream>>>(
        mem0, addr, memq, addrbf, qacc + 3 * 160, ehist, chist, ssum4, e,
        e + 2 * N_LOC, craw8 + 2 * 1056);
    tail<<<160, 256, 0, stream>>>(craw8 + 2 * 1056, hbuf, W_ih, W_hh, b_hh, gix,
        gacc4 + 2 * 1536, hbuf, hout, ssum4, 3, 1, W_er, b_er, W_ch, b_cd, W_q, b_q,
        u_sh, b_sh, candx, ehist + 3 * C, chist + 3 * C, qacc + 4 * 160,
        cnt + 2, flg + 2);
    // step 4 (no e write, no next-step projections)
    big_pass<3, false, false><<<GRID_BIG, 256, 0, stream>>>(
        mem0, addr, memq, addrbf, qacc + 4 * 160, ehist, chist, ssum4, e, e,
        craw8 + 3 * 1056);
    tail<<<96, 256, 0, stream>>>(craw8 + 3 * 1056, hbuf, W_ih, W_hh, b_hh, gix,
        gacc4 + 3 * 1536, hbuf, hout, ssum4, 4, 0, W_er, b_er, W_ch, b_cd, W_q, b_q,
        u_sh, b_sh, candx, ehist + 4 * C, chist + 4 * C, qacc, cnt + 3, flg + 3);
}